// Round 8
// baseline (176.132 us; speedup 1.0000x reference)
//
#include <hip/hip_runtime.h>
#include <hip/hip_bf16.h>

// Problem constants (fixed by reference setup_inputs)
constexpr int NWIN = 49;     // 7x7 windows
constexpr int QLD  = 52;     // padded row length for 49-length rows (13 float4)

// workspace layout (float offsets)
constexpr int OFF_WS   = 0;            // [8][64][52]      = 26624 (bt, s, win)
constexpr int OFF_Q    = 26624;        // [2][128][4][52]  = 53248 (b, d, t, n)
constexpr int OFF_QSP  = 79872;        // [2][4][128][64]  = 65536 (b, t, d, s)
constexpr int OFF_A12  = 145408;       // [2][3][64][64]
constexpr int OFF_A12T = 169984;
constexpr int OFF_A21  = 194560;
constexpr int OFF_A21T = 219136;
constexpr int OFF_BAR  = 243712;       // 640 ints, zeroed per launch

// barrier counter layout (ints from OFF_BAR); counters 128 B apart so RMWs
// land on distinct LLC lines (parallel service, no line ping-pong)
constexpr int B0   = 0;      // stage 0: groups at B0 + g*32 (g=blk&7), root at B0+256
constexpr int B1   = 288;    // stage 1: groups at B1 + g*32, root at B1+256 (=544)
constexpr int C2   = 576;    // stage 2: single counter (6 arrivals)

// ---------------------------------------------------------------------------
// Grid barrier, contention-engineered:
//  - arrival: 1 RMW per block on one of 8 spread counters (32 serialized each),
//    last-of-group promotes to root (8 RMWs total).
//  - wait: atomic LOADS (no exclusive ownership) + s_sleep backoff.
// Safe by capacity: grid=256 blocks, 64 KB LDS, 256-thread blocks -> 1 block/CU
// co-resident on 256 CUs, so the spin always completes.
__device__ __forceinline__ void bar_arrive(int* base) {
    __threadfence();                       // release: L2 writeback (covers block's stores)
    int g = (int)(blockIdx.x & 7);
    int prev = __hip_atomic_fetch_add(&base[g * 32], 1, __ATOMIC_ACQ_REL,
                                      __HIP_MEMORY_SCOPE_AGENT);
    if (prev == 31)
        __hip_atomic_fetch_add(&base[256], 1, __ATOMIC_ACQ_REL,
                               __HIP_MEMORY_SCOPE_AGENT);
}
__device__ __forceinline__ void bar_wait(int* base) {
    while (__hip_atomic_load(&base[256], __ATOMIC_ACQUIRE,
                             __HIP_MEMORY_SCOPE_AGENT) < 8)
        __builtin_amdgcn_s_sleep(2);
    __threadfence();                       // acquire: invalidate stale local lines
}

// ---------------------------------------------------------------------------
// Phase 1 unit: u < 392 -> scatter window; else q head. (proven bodies)
__device__ __forceinline__ void front_unit(int u, const int* __restrict__ mask,
                                           const float* __restrict__ feats,
                                           const float* __restrict__ Wh,
                                           float* __restrict__ ws,
                                           float* __restrict__ q, float* SMEM) {
    if (u < 392) {
        // ws[bt][s][win] = sum over window pixels with label s of 1/sm.
        // sum_win ws[bt][s][:] == pixel count of label s. Pad cols 49..51 = 0.
        int win = u % NWIN;
        int bt  = u / NWIN;
        int wy = win / 7, wx = win % 7;
        float* loc = SMEM;                           // 64 floats
        if (threadIdx.x < 64) loc[threadIdx.x] = 0.f;
        __syncthreads();
        const int* base = mask + bt * 65536 + (wy * 32) * 256 + wx * 32;
        #pragma unroll
        for (int it = 0; it < 16; ++it) {
            int idx = it * 256 + (int)threadIdx.x;
            int r = idx >> 6, c = idx & 63;
            int s = base[r * 256 + c];
            int y = wy * 32 + r, x = wx * 32 + c;
            float w = 1.f;
            if (y >= 32 && y < 224) w *= 0.5f;       // row coverage = 2
            if (x >= 32 && x < 224) w *= 0.5f;       // col coverage = 2
            atomicAdd(&loc[s], w);
        }
        __syncthreads();
        if (threadIdx.x < 64) {
            ws[(bt * 64 + (int)threadIdx.x) * QLD + win] = loc[threadIdx.x];
        } else if (win == 0) {
            int s = threadIdx.x & 63;
            int col = 49 + (int)(threadIdx.x >> 6) - 1;   // 49,50,51
            ws[(bt * 64 + s) * QLD + col] = 0.f;
        }
    } else {
        // q[b][d][t][n] = normalize_d(feats[b,n,:,t] @ Wh[:,d])
        int bid = u - 392;
        int n = bid % NWIN, b = bid / NWIN;
        float4* f4    = (float4*)(SMEM + 64);        // 512 float4
        float4* psum4 = f4 + 512;                    // 256 float4
        float4* red4  = psum4 + 256;                 // 2 float4
        const float4* fp4 = (const float4*)(feats + (size_t)(b * NWIN + n) * 2048);
        for (int i = threadIdx.x; i < 512; i += 256) f4[i] = fp4[i];
        __syncthreads();

        int d = threadIdx.x & 127, ch = threadIdx.x >> 7;
        float a0 = 0.f, a1 = 0.f, a2 = 0.f, a3 = 0.f;
        const float* wp = Wh + d;
        int c0 = ch * 256;
        #pragma unroll 8
        for (int c = c0; c < c0 + 256; ++c) {
            float w = wp[c * 128];
            float4 fv = f4[c];
            a0 += fv.x * w; a1 += fv.y * w; a2 += fv.z * w; a3 += fv.w * w;
        }
        psum4[threadIdx.x] = make_float4(a0, a1, a2, a3);
        __syncthreads();

        float4 A;
        if (threadIdx.x < 128) {
            float4 p0 = psum4[threadIdx.x], p1 = psum4[128 + threadIdx.x];
            A = make_float4(p0.x + p1.x, p0.y + p1.y, p0.z + p1.z, p0.w + p1.w);
            float sx = A.x * A.x, sy = A.y * A.y, sz = A.z * A.z, sw = A.w * A.w;
            for (int off = 32; off; off >>= 1) {
                sx += __shfl_down(sx, off); sy += __shfl_down(sy, off);
                sz += __shfl_down(sz, off); sw += __shfl_down(sw, off);
            }
            if ((threadIdx.x & 63) == 0) red4[threadIdx.x >> 6] = make_float4(sx, sy, sz, sw);
        }
        __syncthreads();
        if (threadIdx.x < 128) {
            float4 r0 = red4[0], r1 = red4[1];
            float ix = 1.f / fmaxf(sqrtf(r0.x + r1.x), 1e-12f);
            float iy = 1.f / fmaxf(sqrtf(r0.y + r1.y), 1e-12f);
            float iz = 1.f / fmaxf(sqrtf(r0.z + r1.z), 1e-12f);
            float iw = 1.f / fmaxf(sqrtf(r0.w + r1.w), 1e-12f);
            float* qb = q + (size_t)(b * 128 + d) * 4 * QLD + n;
            qb[0 * QLD] = A.x * ix;
            qb[1 * QLD] = A.y * iy;
            qb[2 * QLD] = A.z * iz;
            qb[3 * QLD] = A.w * iw;
        }
    }
}

// ---------------------------------------------------------------------------
// Chain helpers (proven): XOR-4-swizzled LDS, register prefetch.
// Layout: element (r,k) at M[r*64 + (((k>>2)^(r&15))<<2)+(k&3)].
__device__ __forceinline__ void dump_mat(float* M, const float4* v) {
    #pragma unroll
    for (int it = 0; it < 4; ++it) {
        int idx = it * 256 + (int)threadIdx.x;
        int r = idx >> 4, c4 = (idx & 15) << 2;
        *(float4*)&M[r * 64 + (c4 ^ ((r & 15) << 2))] = v[it];
    }
}

__device__ __forceinline__ void mmh_sw(float* acc, const float* Ra, const float* Rb) {
    int lt = threadIdx.x & 127;
    int nl = lt >> 3, ml = lt & 7;
    int sxa = nl << 2;
    #pragma unroll
    for (int k0 = 0; k0 < 64; k0 += 4) {
        float4 av[4], bv[8];
        #pragma unroll
        for (int i = 0; i < 4; ++i)
            av[i] = *(const float4*)&Ra[(nl + 16 * i) * 64 + (k0 ^ sxa)];
        #pragma unroll
        for (int j = 0; j < 8; ++j) {
            int m = ml + 8 * j;
            bv[j] = *(const float4*)&Rb[m * 64 + (k0 ^ ((m & 15) << 2))];
        }
        #pragma unroll
        for (int i = 0; i < 4; ++i)
            #pragma unroll
            for (int j = 0; j < 8; ++j)
                acc[i * 8 + j] += av[i].x * bv[j].x + av[i].y * bv[j].y
                                + av[i].z * bv[j].z + av[i].w * bv[j].w;
    }
}

__device__ __forceinline__ void wrh_sw(float* M, const float* acc) {
    int lt = threadIdx.x & 127;
    int nl = lt >> 3, ml = lt & 7;
    #pragma unroll
    for (int i = 0; i < 4; ++i)
        #pragma unroll
        for (int j = 0; j < 8; ++j) {
            int r = nl + 16 * i, k = ml + 8 * j;
            M[r * 64 + (((k & ~3) ^ ((r & 15) << 2)) | (k & 3))] = acc[i * 8 + j];
        }
}

__device__ __forceinline__ void mm256_sw(float* acc, const float* Ra, const float* Rb) {
    int tid = threadIdx.x;
    int nl = tid >> 4, ml = tid & 15;
    int sxa = nl << 2, sxb = ml << 2;
    #pragma unroll
    for (int i = 0; i < 16; ++i) acc[i] = 0.f;
    #pragma unroll 4
    for (int k0 = 0; k0 < 64; k0 += 4) {
        float4 av[4], bv[4];
        #pragma unroll
        for (int i = 0; i < 4; ++i)
            av[i] = *(const float4*)&Ra[(nl + 16 * i) * 64 + (k0 ^ sxa)];
        #pragma unroll
        for (int j = 0; j < 4; ++j)
            bv[j] = *(const float4*)&Rb[(ml + 16 * j) * 64 + (k0 ^ sxb)];
        #pragma unroll
        for (int i = 0; i < 4; ++i)
            #pragma unroll
            for (int j = 0; j < 4; ++j)
                acc[i * 4 + j] += av[i].x * bv[j].x + av[i].y * bv[j].y
                                + av[i].z * bv[j].z + av[i].w * bv[j].w;
    }
}

__device__ __forceinline__ void store_loss(const float* acc, float* __restrict__ aa,
                                           float* __restrict__ out, float* red) {
    int tid = threadIdx.x;
    int nl = tid >> 4, ml = tid & 15;
    #pragma unroll
    for (int i = 0; i < 4; ++i)
        #pragma unroll
        for (int j = 0; j < 4; ++j)
            aa[(nl + 16 * i) * 64 + (ml + 16 * j)] = acc[i * 4 + j];
    int l = tid & 63;
    float part = 0.f;
    #pragma unroll
    for (int i = 0; i < 4; ++i) {
        float rsum = acc[i * 4 + 0] + acc[i * 4 + 1] + acc[i * 4 + 2] + acc[i * 4 + 3];
        rsum += __shfl_down(rsum, 8, 16);
        rsum += __shfl_down(rsum, 4, 16);
        rsum += __shfl_down(rsum, 2, 16);
        rsum += __shfl_down(rsum, 1, 16);
        float dv = __shfl(acc[5 * i], (l & 48) | nl, 64);
        if ((l & 15) == 0) part += logf(rsum + 6.4e-19f) - logf(dv + 1e-20f);
    }
    for (int off = 32; off; off >>= 1) part += __shfl_down(part, off);
    if (l == 0) red[tid >> 6] = part;
    __syncthreads();
    if (tid == 0) atomicAdd(out, (red[0] + red[1] + red[2] + red[3]) * (1.f / 128.f));
}

// ---------------------------------------------------------------------------
// THE kernel: all phases fused, grid = 256 blocks x 256 threads.
__global__ void __launch_bounds__(256, 1)
k_all(const int* __restrict__ mask, const float* __restrict__ feats,
      const float* __restrict__ Wh, float* __restrict__ ws,
      float* __restrict__ q, float* __restrict__ qsp,
      float* __restrict__ a12, float* __restrict__ a12T,
      float* __restrict__ a21, float* __restrict__ a21T,
      float* __restrict__ out, int* __restrict__ bars) {
    __shared__ __align__(16) float SMEM[16384];     // 64 KB, reused per phase
    const int blk = blockIdx.x;
    const int tid = threadIdx.x;

    // ---- phase 1: front (490 units over 256 blocks, <=2 serial units/block)
    front_unit(blk, mask, feats, Wh, ws, q, SMEM);
    if (blk < 234) {
        __syncthreads();
        front_unit(blk + 256, mask, feats, Wh, ws, q, SMEM);
    }
    // ---- barrier 0 (all arrive, all wait)
    __syncthreads();
    if (tid == 0) { bar_arrive(bars + B0); bar_wait(bars + B0); }
    __syncthreads();

    // ---- phase 2: qsp[b][t][d][s], one output per thread (65536 threads)
    {
        int t2 = blk * 256 + tid;
        int s = t2 & 63;
        int d = (t2 >> 6) & 127;
        int t = (t2 >> 13) & 3;
        int b = t2 >> 15;
        const float4* qrow = (const float4*)(q + (size_t)((b * 128 + d) * 4 + t) * QLD);
        const float4* wrow = (const float4*)(ws + (size_t)((b * 4 + t) * 64 + s) * QLD);
        float acc = 0.f, den = 0.f;
        #pragma unroll
        for (int i = 0; i < 13; ++i) {
            float4 w = wrow[i];
            float4 qv = qrow[i];
            den += w.x + w.y + w.z + w.w;
            acc += qv.x * w.x + qv.y * w.y + qv.z * w.z + qv.w * w.w;
        }
        qsp[t2] = acc / (den + 1e-20f);
    }
    // ---- barrier 1 (all arrive; only blocks 0..5 wait, the rest exit)
    __syncthreads();
    if (tid == 0) bar_arrive(bars + B1);
    if (blk >= 6) return;
    if (tid == 0) bar_wait(bars + B1);
    __syncthreads();

    // ---- phase 3: As + zero_softmax (blocks 0..5)
    {
        int t = blk % 3, b = blk / 3;
        if (blk == 0 && tid == 0) out[0] = 0.f;      // loss accumulator
        float4* qaT4 = (float4*)SMEM;                // [s][d-swizzled] 32 KB
        float4* qbT4 = qaT4 + 2048;                  // 32 KB

        {
            const float4* gA = (const float4*)(qsp + (size_t)(b * 4 + t) * 8192);
            const float4* gB = (const float4*)(qsp + (size_t)(b * 4 + t + 1) * 8192);
            float* qaF = (float*)qaT4;
            float* qbF = (float*)qbT4;
            #pragma unroll
            for (int it = 0; it < 8; ++it) {
                int idx = it * 256 + tid;            // float4 index over [d][s/4]
                int d = idx >> 4, s0 = (idx & 15) << 2;
                float4 va = gA[idx];
                float4 vb = gB[idx];
                int g = d >> 2, c = d & 3;
                #pragma unroll
                for (int u = 0; u < 4; ++u) {
                    int s = s0 + u;
                    int w = (s * 32 + (g ^ (s & 31))) * 4 + c;
                    float fa = (u == 0) ? va.x : (u == 1) ? va.y : (u == 2) ? va.z : va.w;
                    float fb = (u == 0) ? vb.x : (u == 1) ? vb.y : (u == 2) ? vb.z : vb.w;
                    qaF[w] = fa;
                    qbF[w] = fb;
                }
            }
        }
        __syncthreads();

        const int nl = tid >> 4, ml = tid & 15;
        float acc[16];
        #pragma unroll
        for (int i = 0; i < 16; ++i) acc[i] = 0.f;
        #pragma unroll 8
        for (int k4 = 0; k4 < 32; ++k4) {
            float4 av[4], bv[4];
            #pragma unroll
            for (int i = 0; i < 4; ++i) { int n = nl + 16 * i; av[i] = qaT4[n * 32 + (k4 ^ (n & 31))]; }
            #pragma unroll
            for (int j = 0; j < 4; ++j) { int m = ml + 16 * j; bv[j] = qbT4[m * 32 + (k4 ^ (m & 31))]; }
            #pragma unroll
            for (int i = 0; i < 4; ++i)
                #pragma unroll
                for (int j = 0; j < 4; ++j)
                    acc[i * 4 + j] += av[i].x * bv[j].x + av[i].y * bv[j].y
                                    + av[i].z * bv[j].z + av[i].w * bv[j].w;
        }
        __syncthreads();

        float* eb = (float*)qaT4;          // [64][65]
        float* rs = (float*)qbT4;          // [64]
        float* cs = rs + 64;               // [64]
        #pragma unroll
        for (int i = 0; i < 4; ++i)
            #pragma unroll
            for (int j = 0; j < 4; ++j) {
                int n = nl + 16 * i, m = ml + 16 * j;
                float x = acc[i * 4 + j] * (1.f / 0.07f);
                float e = expf(x) - 1.f;
                eb[n * 65 + m] = e * e;
            }
        __syncthreads();
        if (tid < 128) {
            int r = tid & 63; bool isrow = tid < 64;
            float a = 0.f;
            #pragma unroll
            for (int k = 0; k < 64; ++k) a += isrow ? eb[r * 65 + k] : eb[k * 65 + r];
            (isrow ? rs : cs)[r] = a + 1e-5f;
        }
        __syncthreads();
        float* p12  = a12  + (b * 3 + t) * 4096;
        float* p12T = a12T + (b * 3 + t) * 4096;
        float* p21  = a21  + (b * 3 + t) * 4096;
        float* p21T = a21T + (b * 3 + t) * 4096;
        #pragma unroll
        for (int i = 0; i < 4; ++i)
            #pragma unroll
            for (int j = 0; j < 4; ++j) {
                int n = nl + 16 * i, m = ml + 16 * j;
                float v   = eb[n * 65 + m];
                float v12 = v / rs[n];           // A12[n][m]
                float v21 = v / cs[m];           // A21[m][n]
                p12 [n * 64 + m] = v12;
                p12T[m * 64 + n] = v12;
                p21 [m * 64 + n] = v21;
                p21T[n * 64 + m] = v21;          // A21^T[n][m]
            }
    }
    // ---- barrier 2 (6 arrive; blocks 0..3 wait, 4..5 exit)
    __syncthreads();
    if (tid == 0) {
        __threadfence();
        __hip_atomic_fetch_add(&bars[C2], 1, __ATOMIC_ACQ_REL, __HIP_MEMORY_SCOPE_AGENT);
    }
    if (blk >= 4) return;
    if (tid == 0) {
        while (__hip_atomic_load(&bars[C2], __ATOMIC_ACQUIRE,
                                 __HIP_MEMORY_SCOPE_AGENT) < 6)
            __builtin_amdgcn_s_sleep(2);
        __threadfence();
    }
    __syncthreads();

    // ---- phase 4: chain matmuls + fused loss (blocks 0..3)
    {
        int path = blk & 1, b = blk >> 1;
        float* M0 = SMEM;
        float* M1 = SMEM + 4096;
        float* M2 = SMEM + 8192;
        float* M3 = SMEM + 12288;

        const float4* L0 = (const float4*)(a12  + (b * 3 + 0) * 4096);  // A12_0 rows
        const float4* L1 = (const float4*)(a12T + (b * 3 + 1) * 4096);  // A12_1^T rows
        const float4* L2 = (const float4*)(a21T + (b * 3 + 0) * 4096);  // A21_0^T rows
        const float4* L3 = (const float4*)(a21  + (b * 3 + 1) * 4096);  // A21_1 rows
        const float4* L4 = (const float4*)(a12T + (b * 3 + 2) * 4096);  // A12_2^T rows
        const float4* L5 = (const float4*)(a21  + (b * 3 + 2) * 4096);  // A21_2 rows

        float4 pf[6][4];
        #pragma unroll
        for (int it = 0; it < 4; ++it) {
            int idx = it * 256 + tid;
            pf[0][it] = L0[idx];
            pf[1][it] = L1[idx];
            pf[2][it] = L2[idx];
            pf[3][it] = L3[idx];
        }
        if (path) {
            #pragma unroll
            for (int it = 0; it < 4; ++it) {
                int idx = it * 256 + tid;
                pf[4][it] = L4[idx];
                pf[5][it] = L5[idx];
            }
        }
        __syncthreads();                 // phase-3 LDS reads fully retired
        dump_mat(M0, pf[0]);
        dump_mat(M1, pf[1]);
        dump_mat(M2, pf[2]);
        dump_mat(M3, pf[3]);
        __syncthreads();

        int half = tid >> 7;
        float hacc[32];
        #pragma unroll
        for (int i = 0; i < 32; ++i) hacc[i] = 0.f;
        mmh_sw(hacc, half ? M2 : M0, half ? M3 : M1);   // P | R1T
        __syncthreads();
        wrh_sw(half ? M3 : M1, hacc);                    // P -> M1, R1T -> M3
        if (path) { dump_mat(M0, pf[4]); dump_mat(M2, pf[5]); }
        __syncthreads();

        if (path == 0) {
            float acc[16];
            mm256_sw(acc, M1, M3);                       // aa1 = P @ R1
            store_loss(acc, out + 1 + b * 4096, out, M0);
        } else {
            float hacc2[32];
            #pragma unroll
            for (int i = 0; i < 32; ++i) hacc2[i] = 0.f;
            mmh_sw(hacc2, half ? M3 : M1, half ? M2 : M0);  // L | RT
            __syncthreads();
            wrh_sw(half ? M1 : M0, hacc2);                  // L -> M0, RT -> M1
            __syncthreads();
            float acc[16];
            mm256_sw(acc, M0, M1);                          // aa2 = L @ R
            store_loss(acc, out + 1 + (2 + b) * 4096, out, M2);
        }
    }
}

// ---------------------------------------------------------------------------
extern "C" void kernel_launch(void* const* d_in, const int* in_sizes, int n_in,
                              void* d_out, int out_size, void* d_ws, size_t ws_size,
                              hipStream_t stream) {
    const float* feats = (const float*)d_in[0];
    const float* Wh    = (const float*)d_in[1];
    const int*   mask  = (const int*)d_in[2];
    float* out = (float*)d_out;
    float* ws  = (float*)d_ws;

    float* ws_sums = ws + OFF_WS;
    float* q       = ws + OFF_Q;
    float* qsp     = ws + OFF_QSP;
    float* a12     = ws + OFF_A12;
    float* a12T    = ws + OFF_A12T;
    float* a21     = ws + OFF_A21;
    float* a21T    = ws + OFF_A21T;
    int*   bars    = (int*)(ws + OFF_BAR);

    hipMemsetAsync(bars, 0, 640 * sizeof(int), stream);
    k_all<<<256, 256, 0, stream>>>(mask, feats, Wh, ws_sums, q, qsp,
                                   a12, a12T, a21, a21T, out, bars);
}

// Round 9
// 132.779 us; speedup vs baseline: 1.3265x; 1.3265x over previous
//
#include <hip/hip_runtime.h>
#include <hip/hip_bf16.h>

// Problem constants (fixed by reference setup_inputs)
constexpr int NWIN = 49;     // 7x7 windows
constexpr int QLD  = 52;     // padded row length for 49-length rows (13 float4)

// workspace layout (float offsets)
constexpr int OFF_WS   = 0;            // [8][64][52]      = 26624 (bt, s, win)
constexpr int OFF_Q    = 26624;        // [2][128][4][52]  = 53248 (b, d, t, n)
constexpr int OFF_QSP  = 79872;        // [2][4][128][64]  = 65536 (b, t, d, s)
constexpr int OFF_A12  = 145408;       // [2][3][64][64]
constexpr int OFF_A12T = 169984;
constexpr int OFF_A21  = 194560;
constexpr int OFF_A21T = 219136;
constexpr int OFF_BAR  = 243712;       // 640 ints, zeroed per launch

// barrier counters: 8 group counters 128 B apart + root at [256]
constexpr int B0 = 0;        // stage 0 (front done):  384 arrivals
constexpr int B1 = 288;      // stage 1 (qsp done):    384 arrivals
constexpr int C2 = 576;      // stage 2 (As done):     6 arrivals

// ---------------------------------------------------------------------------
// Fences: one explicit agent fence per transition instead of per-op cache
// maintenance. RELAXED atomics carry no per-iteration buffer_inv.
__device__ __forceinline__ void fence_rel() {
    __builtin_amdgcn_fence(__ATOMIC_RELEASE, "agent");   // L2 writeback
}
__device__ __forceinline__ void fence_acq() {
    __builtin_amdgcn_fence(__ATOMIC_ACQUIRE, "agent");   // L2/L1 invalidate
}
// arrival: 1 relaxed RMW on one of 8 spread lines; 48th of group bumps root.
__device__ __forceinline__ void arrive8(int* base) {
    int g = (int)(blockIdx.x & 7);
    int prev = __hip_atomic_fetch_add(&base[g * 32], 1, __ATOMIC_RELAXED,
                                      __HIP_MEMORY_SCOPE_AGENT);
    if (prev == 47)
        __hip_atomic_fetch_add(&base[256], 1, __ATOMIC_RELAXED,
                               __HIP_MEMORY_SCOPE_AGENT);
}
__device__ __forceinline__ void poll8(int* base) {
    while (__hip_atomic_load(&base[256], __ATOMIC_RELAXED,
                             __HIP_MEMORY_SCOPE_AGENT) < 8)
        __builtin_amdgcn_s_sleep(4);
}

// ---------------------------------------------------------------------------
// Phase 1 unit: u < 392 -> scatter window; else q head. (proven bodies)
__device__ __forceinline__ void front_unit(int u, const int* __restrict__ mask,
                                           const float* __restrict__ feats,
                                           const float* __restrict__ Wh,
                                           float* __restrict__ ws,
                                           float* __restrict__ q, float* SMEM) {
    if (u < 392) {
        // ws[bt][s][win] = sum over window pixels with label s of 1/sm.
        // sum_win ws[bt][s][:] == pixel count of label s. Pad cols 49..51 = 0.
        int win = u % NWIN;
        int bt  = u / NWIN;
        int wy = win / 7, wx = win % 7;
        float* loc = SMEM;                           // 64 floats
        if (threadIdx.x < 64) loc[threadIdx.x] = 0.f;
        __syncthreads();
        const int* base = mask + bt * 65536 + (wy * 32) * 256 + wx * 32;
        #pragma unroll
        for (int it = 0; it < 16; ++it) {
            int idx = it * 256 + (int)threadIdx.x;
            int r = idx >> 6, c = idx & 63;
            int s = base[r * 256 + c];
            int y = wy * 32 + r, x = wx * 32 + c;
            float w = 1.f;
            if (y >= 32 && y < 224) w *= 0.5f;       // row coverage = 2
            if (x >= 32 && x < 224) w *= 0.5f;       // col coverage = 2
            atomicAdd(&loc[s], w);
        }
        __syncthreads();
        if (threadIdx.x < 64) {
            ws[(bt * 64 + (int)threadIdx.x) * QLD + win] = loc[threadIdx.x];
        } else if (win == 0) {
            int s = threadIdx.x & 63;
            int col = 49 + (int)(threadIdx.x >> 6) - 1;   // 49,50,51
            ws[(bt * 64 + s) * QLD + col] = 0.f;
        }
    } else {
        // q[b][d][t][n] = normalize_d(feats[b,n,:,t] @ Wh[:,d])
        int bid = u - 392;
        int n = bid % NWIN, b = bid / NWIN;
        float4* f4    = (float4*)(SMEM + 64);        // 512 float4
        float4* psum4 = f4 + 512;                    // 256 float4
        float4* red4  = psum4 + 256;                 // 2 float4
        const float4* fp4 = (const float4*)(feats + (size_t)(b * NWIN + n) * 2048);
        for (int i = threadIdx.x; i < 512; i += 256) f4[i] = fp4[i];
        __syncthreads();

        int d = threadIdx.x & 127, ch = threadIdx.x >> 7;
        float a0 = 0.f, a1 = 0.f, a2 = 0.f, a3 = 0.f;
        const float* wp = Wh + d;
        int c0 = ch * 256;
        #pragma unroll 8
        for (int c = c0; c < c0 + 256; ++c) {
            float w = wp[c * 128];
            float4 fv = f4[c];
            a0 += fv.x * w; a1 += fv.y * w; a2 += fv.z * w; a3 += fv.w * w;
        }
        psum4[threadIdx.x] = make_float4(a0, a1, a2, a3);
        __syncthreads();

        float4 A;
        if (threadIdx.x < 128) {
            float4 p0 = psum4[threadIdx.x], p1 = psum4[128 + threadIdx.x];
            A = make_float4(p0.x + p1.x, p0.y + p1.y, p0.z + p1.z, p0.w + p1.w);
            float sx = A.x * A.x, sy = A.y * A.y, sz = A.z * A.z, sw = A.w * A.w;
            for (int off = 32; off; off >>= 1) {
                sx += __shfl_down(sx, off); sy += __shfl_down(sy, off);
                sz += __shfl_down(sz, off); sw += __shfl_down(sw, off);
            }
            if ((threadIdx.x & 63) == 0) red4[threadIdx.x >> 6] = make_float4(sx, sy, sz, sw);
        }
        __syncthreads();
        if (threadIdx.x < 128) {
            float4 r0 = red4[0], r1 = red4[1];
            float ix = 1.f / fmaxf(sqrtf(r0.x + r1.x), 1e-12f);
            float iy = 1.f / fmaxf(sqrtf(r0.y + r1.y), 1e-12f);
            float iz = 1.f / fmaxf(sqrtf(r0.z + r1.z), 1e-12f);
            float iw = 1.f / fmaxf(sqrtf(r0.w + r1.w), 1e-12f);
            float* qb = q + (size_t)(b * 128 + d) * 4 * QLD + n;
            qb[0 * QLD] = A.x * ix;
            qb[1 * QLD] = A.y * iy;
            qb[2 * QLD] = A.z * iz;
            qb[3 * QLD] = A.w * iw;
        }
    }
}

// ---------------------------------------------------------------------------
// Chain helpers (proven): XOR-4-swizzled LDS, register prefetch.
// Layout: element (r,k) at M[r*64 + (((k>>2)^(r&15))<<2)+(k&3)].
__device__ __forceinline__ void dump_mat(float* M, const float4* v) {
    #pragma unroll
    for (int it = 0; it < 4; ++it) {
        int idx = it * 256 + (int)threadIdx.x;
        int r = idx >> 4, c4 = (idx & 15) << 2;
        *(float4*)&M[r * 64 + (c4 ^ ((r & 15) << 2))] = v[it];
    }
}

__device__ __forceinline__ void mmh_sw(float* acc, const float* Ra, const float* Rb) {
    int lt = threadIdx.x & 127;
    int nl = lt >> 3, ml = lt & 7;
    int sxa = nl << 2;
    #pragma unroll
    for (int k0 = 0; k0 < 64; k0 += 4) {
        float4 av[4], bv[8];
        #pragma unroll
        for (int i = 0; i < 4; ++i)
            av[i] = *(const float4*)&Ra[(nl + 16 * i) * 64 + (k0 ^ sxa)];
        #pragma unroll
        for (int j = 0; j < 8; ++j) {
            int m = ml + 8 * j;
            bv[j] = *(const float4*)&Rb[m * 64 + (k0 ^ ((m & 15) << 2))];
        }
        #pragma unroll
        for (int i = 0; i < 4; ++i)
            #pragma unroll
            for (int j = 0; j < 8; ++j)
                acc[i * 8 + j] += av[i].x * bv[j].x + av[i].y * bv[j].y
                                + av[i].z * bv[j].z + av[i].w * bv[j].w;
    }
}

__device__ __forceinline__ void wrh_sw(float* M, const float* acc) {
    int lt = threadIdx.x & 127;
    int nl = lt >> 3, ml = lt & 7;
    #pragma unroll
    for (int i = 0; i < 4; ++i)
        #pragma unroll
        for (int j = 0; j < 8; ++j) {
            int r = nl + 16 * i, k = ml + 8 * j;
            M[r * 64 + (((k & ~3) ^ ((r & 15) << 2)) | (k & 3))] = acc[i * 8 + j];
        }
}

__device__ __forceinline__ void mm256_sw(float* acc, const float* Ra, const float* Rb) {
    int tid = threadIdx.x;
    int nl = tid >> 4, ml = tid & 15;
    int sxa = nl << 2, sxb = ml << 2;
    #pragma unroll
    for (int i = 0; i < 16; ++i) acc[i] = 0.f;
    #pragma unroll 4
    for (int k0 = 0; k0 < 64; k0 += 4) {
        float4 av[4], bv[4];
        #pragma unroll
        for (int i = 0; i < 4; ++i)
            av[i] = *(const float4*)&Ra[(nl + 16 * i) * 64 + (k0 ^ sxa)];
        #pragma unroll
        for (int j = 0; j < 4; ++j)
            bv[j] = *(const float4*)&Rb[(ml + 16 * j) * 64 + (k0 ^ sxb)];
        #pragma unroll
        for (int i = 0; i < 4; ++i)
            #pragma unroll
            for (int j = 0; j < 4; ++j)
                acc[i * 4 + j] += av[i].x * bv[j].x + av[i].y * bv[j].y
                                + av[i].z * bv[j].z + av[i].w * bv[j].w;
    }
}

__device__ __forceinline__ void store_loss(const float* acc, float* __restrict__ aa,
                                           float* __restrict__ out, float* red) {
    int tid = threadIdx.x;
    int nl = tid >> 4, ml = tid & 15;
    #pragma unroll
    for (int i = 0; i < 4; ++i)
        #pragma unroll
        for (int j = 0; j < 4; ++j)
            aa[(nl + 16 * i) * 64 + (ml + 16 * j)] = acc[i * 4 + j];
    int l = tid & 63;
    float part = 0.f;
    #pragma unroll
    for (int i = 0; i < 4; ++i) {
        float rsum = acc[i * 4 + 0] + acc[i * 4 + 1] + acc[i * 4 + 2] + acc[i * 4 + 3];
        rsum += __shfl_down(rsum, 8, 16);
        rsum += __shfl_down(rsum, 4, 16);
        rsum += __shfl_down(rsum, 2, 16);
        rsum += __shfl_down(rsum, 1, 16);
        float dv = __shfl(acc[5 * i], (l & 48) | nl, 64);
        if ((l & 15) == 0) part += logf(rsum + 6.4e-19f) - logf(dv + 1e-20f);
    }
    for (int off = 32; off; off >>= 1) part += __shfl_down(part, off);
    if (l == 0) red[tid >> 6] = part;
    __syncthreads();
    if (tid == 0) atomicAdd(out, (red[0] + red[1] + red[2] + red[3]) * (1.f / 128.f));
}

// ---------------------------------------------------------------------------
// THE kernel: all phases fused, grid = 384 blocks x 256 threads.
// Co-residency (barrier safety): 64 KB LDS -> 2 blocks/CU (128<=160 KB),
// VGPR<=256 via launch_bounds(256,2) -> capacity 512 >= 384.
__global__ void __launch_bounds__(256, 2)
k_all(const int* __restrict__ mask, const float* __restrict__ feats,
      const float* __restrict__ Wh, float* __restrict__ ws,
      float* __restrict__ q, float* __restrict__ qsp,
      float* __restrict__ a12, float* __restrict__ a12T,
      float* __restrict__ a21, float* __restrict__ a21T,
      float* __restrict__ out, int* __restrict__ bars) {
    __shared__ __align__(16) float SMEM[16384];     // 64 KB, reused per phase
    const int blk = blockIdx.x;
    const int tid = threadIdx.x;

    // ---- phase 1: front. 490 units over 384 blocks:
    // blocks 0..97: one q unit; 98..203: two scatter units; 204..383: one scatter.
    if (blk < 98) {
        front_unit(392 + blk, mask, feats, Wh, ws, q, SMEM);
    } else {
        front_unit(blk - 98, mask, feats, Wh, ws, q, SMEM);
        if (blk < 204) {
            __syncthreads();
            front_unit(blk + 188, mask, feats, Wh, ws, q, SMEM);
        }
    }
    // ---- barrier 0: 384 arrive; blocks 0..255 wait (they run phase 2)
    __syncthreads();
    if (tid == 0) {
        fence_rel();
        arrive8(bars + B0);
        if (blk < 256) { poll8(bars + B0); fence_acq(); }
    }
    __syncthreads();
    if (blk >= 256) {                    // no phase-2 work: count into bar1, exit
        if (tid == 0) arrive8(bars + B1);
        return;
    }

    // ---- phase 2: qsp[b][t][d][s], one output per thread (65536 threads)
    {
        int t2 = blk * 256 + tid;
        int s = t2 & 63;
        int d = (t2 >> 6) & 127;
        int t = (t2 >> 13) & 3;
        int b = t2 >> 15;
        const float4* qrow = (const float4*)(q + (size_t)((b * 128 + d) * 4 + t) * QLD);
        const float4* wrow = (const float4*)(ws + (size_t)((b * 4 + t) * 64 + s) * QLD);
        float acc = 0.f, den = 0.f;
        #pragma unroll
        for (int i = 0; i < 13; ++i) {
            float4 w = wrow[i];
            float4 qv = qrow[i];
            den += w.x + w.y + w.z + w.w;
            acc += qv.x * w.x + qv.y * w.y + qv.z * w.z + qv.w * w.w;
        }
        qsp[t2] = acc / (den + 1e-20f);
    }
    // ---- barrier 1: 384 arrive; only blocks 0..5 wait
    __syncthreads();
    if (tid == 0) { fence_rel(); arrive8(bars + B1); }
    if (blk >= 6) return;
    if (tid == 0) { poll8(bars + B1); fence_acq(); }
    __syncthreads();

    // ---- phase 3: As + zero_softmax (blocks 0..5)
    {
        int t = blk % 3, b = blk / 3;
        if (blk == 0 && tid == 0) out[0] = 0.f;      // loss accumulator
        float4* qaT4 = (float4*)SMEM;                // [s][d-swizzled] 32 KB
        float4* qbT4 = qaT4 + 2048;                  // 32 KB

        {
            const float4* gA = (const float4*)(qsp + (size_t)(b * 4 + t) * 8192);
            const float4* gB = (const float4*)(qsp + (size_t)(b * 4 + t + 1) * 8192);
            float* qaF = (float*)qaT4;
            float* qbF = (float*)qbT4;
            #pragma unroll
            for (int it = 0; it < 8; ++it) {
                int idx = it * 256 + tid;            // float4 index over [d][s/4]
                int d = idx >> 4, s0 = (idx & 15) << 2;
                float4 va = gA[idx];
                float4 vb = gB[idx];
                int g = d >> 2, c = d & 3;
                #pragma unroll
                for (int u = 0; u < 4; ++u) {
                    int s = s0 + u;
                    int w = (s * 32 + (g ^ (s & 31))) * 4 + c;
                    float fa = (u == 0) ? va.x : (u == 1) ? va.y : (u == 2) ? va.z : va.w;
                    float fb = (u == 0) ? vb.x : (u == 1) ? vb.y : (u == 2) ? vb.z : vb.w;
                    qaF[w] = fa;
                    qbF[w] = fb;
                }
            }
        }
        __syncthreads();

        const int nl = tid >> 4, ml = tid & 15;
        float acc[16];
        #pragma unroll
        for (int i = 0; i < 16; ++i) acc[i] = 0.f;
        #pragma unroll 8
        for (int k4 = 0; k4 < 32; ++k4) {
            float4 av[4], bv[4];
            #pragma unroll
            for (int i = 0; i < 4; ++i) { int n = nl + 16 * i; av[i] = qaT4[n * 32 + (k4 ^ (n & 31))]; }
            #pragma unroll
            for (int j = 0; j < 4; ++j) { int m = ml + 16 * j; bv[j] = qbT4[m * 32 + (k4 ^ (m & 31))]; }
            #pragma unroll
            for (int i = 0; i < 4; ++i)
                #pragma unroll
                for (int j = 0; j < 4; ++j)
                    acc[i * 4 + j] += av[i].x * bv[j].x + av[i].y * bv[j].y
                                    + av[i].z * bv[j].z + av[i].w * bv[j].w;
        }
        __syncthreads();

        float* eb = (float*)qaT4;          // [64][65]
        float* rs = (float*)qbT4;          // [64]
        float* cs = rs + 64;               // [64]
        #pragma unroll
        for (int i = 0; i < 4; ++i)
            #pragma unroll
            for (int j = 0; j < 4; ++j) {
                int n = nl + 16 * i, m = ml + 16 * j;
                float x = acc[i * 4 + j] * (1.f / 0.07f);
                float e = expf(x) - 1.f;
                eb[n * 65 + m] = e * e;
            }
        __syncthreads();
        if (tid < 128) {
            int r = tid & 63; bool isrow = tid < 64;
            float a = 0.f;
            #pragma unroll
            for (int k = 0; k < 64; ++k) a += isrow ? eb[r * 65 + k] : eb[k * 65 + r];
            (isrow ? rs : cs)[r] = a + 1e-5f;
        }
        __syncthreads();
        float* p12  = a12  + (b * 3 + t) * 4096;
        float* p12T = a12T + (b * 3 + t) * 4096;
        float* p21  = a21  + (b * 3 + t) * 4096;
        float* p21T = a21T + (b * 3 + t) * 4096;
        #pragma unroll
        for (int i = 0; i < 4; ++i)
            #pragma unroll
            for (int j = 0; j < 4; ++j) {
                int n = nl + 16 * i, m = ml + 16 * j;
                float v   = eb[n * 65 + m];
                float v12 = v / rs[n];           // A12[n][m]
                float v21 = v / cs[m];           // A21[m][n]
                p12 [n * 64 + m] = v12;
                p12T[m * 64 + n] = v12;
                p21 [m * 64 + n] = v21;
                p21T[n * 64 + m] = v21;          // A21^T[n][m]
            }
    }
    // ---- barrier 2: 6 arrive; blocks 0..3 wait
    __syncthreads();
    if (tid == 0) {
        fence_rel();
        __hip_atomic_fetch_add(&bars[C2], 1, __ATOMIC_RELAXED, __HIP_MEMORY_SCOPE_AGENT);
    }
    if (blk >= 4) return;
    if (tid == 0) {
        while (__hip_atomic_load(&bars[C2], __ATOMIC_RELAXED,
                                 __HIP_MEMORY_SCOPE_AGENT) < 6)
            __builtin_amdgcn_s_sleep(1);
        fence_acq();
    }
    __syncthreads();

    // ---- phase 4: chain matmuls + fused loss (blocks 0..3)
    {
        int path = blk & 1, b = blk >> 1;
        float* M0 = SMEM;
        float* M1 = SMEM + 4096;
        float* M2 = SMEM + 8192;
        float* M3 = SMEM + 12288;

        const float4* L0 = (const float4*)(a12  + (b * 3 + 0) * 4096);  // A12_0 rows
        const float4* L1 = (const float4*)(a12T + (b * 3 + 1) * 4096);  // A12_1^T rows
        const float4* L2 = (const float4*)(a21T + (b * 3 + 0) * 4096);  // A21_0^T rows
        const float4* L3 = (const float4*)(a21  + (b * 3 + 1) * 4096);  // A21_1 rows
        const float4* L4 = (const float4*)(a12T + (b * 3 + 2) * 4096);  // A12_2^T rows
        const float4* L5 = (const float4*)(a21  + (b * 3 + 2) * 4096);  // A21_2 rows

        float4 pf[6][4];
        #pragma unroll
        for (int it = 0; it < 4; ++it) {
            int idx = it * 256 + tid;
            pf[0][it] = L0[idx];
            pf[1][it] = L1[idx];
            pf[2][it] = L2[idx];
            pf[3][it] = L3[idx];
        }
        if (path) {
            #pragma unroll
            for (int it = 0; it < 4; ++it) {
                int idx = it * 256 + tid;
                pf[4][it] = L4[idx];
                pf[5][it] = L5[idx];
            }
        }
        __syncthreads();                 // phase-3 LDS reads fully retired
        dump_mat(M0, pf[0]);
        dump_mat(M1, pf[1]);
        dump_mat(M2, pf[2]);
        dump_mat(M3, pf[3]);
        __syncthreads();

        int half = tid >> 7;
        float hacc[32];
        #pragma unroll
        for (int i = 0; i < 32; ++i) hacc[i] = 0.f;
        mmh_sw(hacc, half ? M2 : M0, half ? M3 : M1);   // P | R1T
        __syncthreads();
        wrh_sw(half ? M3 : M1, hacc);                    // P -> M1, R1T -> M3
        if (path) { dump_mat(M0, pf[4]); dump_mat(M2, pf[5]); }
        __syncthreads();

        if (path == 0) {
            float acc[16];
            mm256_sw(acc, M1, M3);                       // aa1 = P @ R1
            store_loss(acc, out + 1 + b * 4096, out, M0);
        } else {
            float hacc2[32];
            #pragma unroll
            for (int i = 0; i < 32; ++i) hacc2[i] = 0.f;
            mmh_sw(hacc2, half ? M3 : M1, half ? M2 : M0);  // L | RT
            __syncthreads();
            wrh_sw(half ? M1 : M0, hacc2);                  // L -> M0, RT -> M1
            __syncthreads();
            float acc[16];
            mm256_sw(acc, M0, M1);                          // aa2 = L @ R
            store_loss(acc, out + 1 + (2 + b) * 4096, out, M2);
        }
    }
}

// ---------------------------------------------------------------------------
extern "C" void kernel_launch(void* const* d_in, const int* in_sizes, int n_in,
                              void* d_out, int out_size, void* d_ws, size_t ws_size,
                              hipStream_t stream) {
    const float* feats = (const float*)d_in[0];
    const float* Wh    = (const float*)d_in[1];
    const int*   mask  = (const int*)d_in[2];
    float* out = (float*)d_out;
    float* ws  = (float*)d_ws;

    float* ws_sums = ws + OFF_WS;
    float* q       = ws + OFF_Q;
    float* qsp     = ws + OFF_QSP;
    float* a12     = ws + OFF_A12;
    float* a12T    = ws + OFF_A12T;
    float* a21     = ws + OFF_A21;
    float* a21T    = ws + OFF_A21T;
    int*   bars    = (int*)(ws + OFF_BAR);

    hipMemsetAsync(bars, 0, 640 * sizeof(int), stream);
    k_all<<<384, 256, 0, stream>>>(mask, feats, Wh, ws_sums, q, qsp,
                                   a12, a12T, a21, a21T, out, bars);
}